// Round 1
// baseline (356.327 us; speedup 1.0000x reference)
//
#include <hip/hip_runtime.h>

#define NN 50000
#define NE 800000
#define NEB 1563   // ceil(NE/512) edge blocks (2 edges/thread)
#define NHB 3125   // NN/16 projection blocks / node tiles
#define NTILES 3125
// inputs: node_features[NN*64] f32, edge_features[NE*32] f32, src[NE] i32,
//         dst[NE] i32, w_group[160] f32, w_srcattn[96] f32, w_lin[160*64] f32
// out: [NN*64] f32
//
// Algebra: a = ef·wg[0:32] + p1[src] + p2[dst]; t = p3[src]; u = ef·wa[64:96]
//          gamma = e^a / den_src[src]; s = t + gamma*u
// dst-CSR built via hist(rank)+assign; dst-softmax denom = inline segment sum.
// hb[n][160] bf16 row = [bf16(h) | accum] is the GEMM A-matrix, written at the
// same rounding points the old f32->bf16 conversion used (bit-identical GEMM).

typedef __attribute__((ext_vector_type(8))) short bf16x8;  // 8 bf16 (4 VGPRs)
typedef __attribute__((ext_vector_type(4))) short s16x4;
typedef __attribute__((ext_vector_type(4))) float f32x4;
typedef __attribute__((ext_vector_type(4))) int   i32x4;

static __device__ __forceinline__ short f2bf(float f) {
    unsigned int u = __float_as_uint(f);
    u += 0x7FFFu + ((u >> 16) & 1u);       // round-to-nearest-even
    return (short)(u >> 16);
}

// ---------------------------------------------------------------------------
// Pass 0 (fused): blocks [0,NEB): dst histogram + per-edge rank, 2 edges per
// thread for MLP. blocks [NEB,NEB+NHB): per-node projections (16 lanes/node)
//   p1 = h·wg[32:96] ; pd = h·wg[96:160] ; dp[n].y = h·wa[0:64] (p3)
// plus bf16 copy of the h row into hb[n][0:64] for the final GEMM.
// ---------------------------------------------------------------------------
__global__ __launch_bounds__(256) void k_pre(
    const float* __restrict__ h, const int* __restrict__ dst,
    const float* __restrict__ wg, const float* __restrict__ wa,
    int* __restrict__ cnt, int* __restrict__ rank,
    float* __restrict__ p1, float* __restrict__ pd, float* __restrict__ dpf,
    short* __restrict__ hb)
{
    int tid = threadIdx.x;
    if (blockIdx.x < NEB) {
        int e0 = blockIdx.x * 512 + tid;
        if (e0 >= NE) return;
        int e1 = e0 + 256;
        bool v1 = e1 < NE;
        int d0 = dst[e0];
        int d1 = dst[v1 ? e1 : 0];
        int r0 = atomicAdd(&cnt[d0], 1);
        int r1 = v1 ? atomicAdd(&cnt[d1], 1) : 0;
        rank[e0] = r0;
        if (v1) rank[e1] = r1;
        return;
    }
    __shared__ float4 ls[16], ld[16], lt[16];
    if (tid < 16)      ls[tid]      = ((const float4*)wg)[8 + tid];   // wg[32:96)
    else if (tid < 32) ld[tid - 16] = ((const float4*)wg)[8 + tid];   // wg[96:160)
    else if (tid < 48) lt[tid - 32] = ((const float4*)wa)[tid - 32];  // wa[0:64)
    __syncthreads();
    int n = (blockIdx.x - NEB) * 16 + (tid >> 4);
    if (n >= NN) return;
    int l16 = tid & 15;
    float4 v = ((const float4*)(h + (size_t)n * 64))[l16];
    s16x4 hv;
    hv[0] = f2bf(v.x); hv[1] = f2bf(v.y); hv[2] = f2bf(v.z); hv[3] = f2bf(v.w);
    *(s16x4*)(hb + (size_t)n * 160 + l16 * 4) = hv;
    float4 w1 = ls[l16], w2 = ld[l16], w3 = lt[l16];
    float s1 = v.x*w1.x + v.y*w1.y + v.z*w1.z + v.w*w1.w;
    float s2 = v.x*w2.x + v.y*w2.y + v.z*w2.z + v.w*w2.w;
    float s3 = v.x*w3.x + v.y*w3.y + v.z*w3.z + v.w*w3.w;
    #pragma unroll
    for (int m = 8; m; m >>= 1) {
        s1 += __shfl_xor(s1, m);
        s2 += __shfl_xor(s2, m);
        s3 += __shfl_xor(s3, m);
    }
    if (l16 == 0) { p1[n] = s1; pd[n] = s2; dpf[2 * n + 1] = s3; }
}

// ---------------------------------------------------------------------------
// Pass 1: contiguous (order-arbitrary) segment bases from cnt.
// ---------------------------------------------------------------------------
__global__ __launch_bounds__(256) void k_assign(
    const int* __restrict__ cnt, int* __restrict__ off, int* __restrict__ gtotal)
{
    int n = blockIdx.x * 256 + threadIdx.x;
    int lane = threadIdx.x & 63;
    int c = (n < NN) ? cnt[n] : 0;
    int pre = c;
    #pragma unroll
    for (int d = 1; d < 64; d <<= 1) {
        int v = __shfl_up(pre, d);
        if (lane >= d) pre += v;
    }
    int base = 0;
    if (lane == 63) base = atomicAdd(gtotal, pre);
    base = __shfl(base, 63);
    if (n < NN) off[n] = base + pre - c;
}

// ---------------------------------------------------------------------------
// Pass 2: edge scoring + direct CSR routing, 2 edges/thread for MLP.
// recA[pos] = {src, e, e^a, u} via NON-TEMPORAL store: the 16B scatter is
// write-once, never re-read from cache in this kernel -> skip the
// write-allocate RMW fetch (was ~51 MB of FETCH_SIZE).
// ---------------------------------------------------------------------------
__global__ __launch_bounds__(256) void k_edge(
    const float* __restrict__ ef, const int* __restrict__ src,
    const int* __restrict__ dst, const int* __restrict__ rank,
    const float* __restrict__ wg, const float* __restrict__ wa,
    const float* __restrict__ p1, const float* __restrict__ pd,
    float* __restrict__ dpf, const int* __restrict__ off,
    i32x4* __restrict__ recA)
{
    __shared__ float4 lwe[8], lae[8];
    int tid = threadIdx.x;
    if (tid < 8)       lwe[tid]     = ((const float4*)wg)[tid];          // wg[0:32)
    else if (tid < 16) lae[tid - 8] = ((const float4*)wa)[tid - 8 + 16]; // wa[64:96)
    __syncthreads();
    int e0 = blockIdx.x * 512 + tid;
    if (e0 >= NE) return;
    int e1 = e0 + 256;
    bool v1 = e1 < NE;
    int e1c = v1 ? e1 : 0;
    int s0 = src[e0], d0 = dst[e0], k0 = rank[e0];
    int s1 = src[e1c], d1 = dst[e1c], k1 = rank[e1c];
    float p1a = p1[s0], pda = pd[d0];
    float p1b = p1[s1], pdb = pd[d1];
    int o0 = off[d0], o1 = off[d1];
    const float4* ea = (const float4*)ef + (unsigned)e0 * 8u;
    const float4* eb = (const float4*)ef + (unsigned)e1c * 8u;
    float a0 = 0.f, u0 = 0.f, a1 = 0.f, u1 = 0.f;
    #pragma unroll
    for (int q = 0; q < 8; ++q) {
        float4 x = ea[q], y = eb[q];
        float4 w = lwe[q], w2 = lae[q];
        a0 += x.x*w.x  + x.y*w.y  + x.z*w.z  + x.w*w.w;
        u0 += x.x*w2.x + x.y*w2.y + x.z*w2.z + x.w*w2.w;
        a1 += y.x*w.x  + y.y*w.y  + y.z*w.z  + y.w*w.w;
        u1 += y.x*w2.x + y.y*w2.y + y.z*w2.z + y.w*w2.w;
    }
    float ev0 = __expf(a0 + p1a + pda);
    float ev1 = __expf(a1 + p1b + pdb);
    atomicAdd(&dpf[2 * s0], ev0);                 // den_src; fire-and-forget
    if (v1) atomicAdd(&dpf[2 * s1], ev1);
    i32x4 rc0 = (i32x4){s0, e0, __float_as_int(ev0), __float_as_int(u0)};
    __builtin_nontemporal_store(rc0, recA + (o0 + k0));
    if (v1) {
        i32x4 rc1 = (i32x4){s1, e1, __float_as_int(ev1), __float_as_int(u1)};
        __builtin_nontemporal_store(rc1, recA + (o1 + k1));
    }
}

// ---------------------------------------------------------------------------
// Pass 3: wave-per-node segmented softmax-reduce, 8-wide main loop (deeper
// load ILP), hardware rcp instead of full-precision div (1 ulp; invisible
// under the bf16 output rounding), 32-bit gather indices, bf16 accum store
// into hb[n][64:160] (same rounding point the GEMM applied anyway).
// ef rows: lanes>=32 take the odd record of each pair; one shfl_xor(32) fold.
// ---------------------------------------------------------------------------
__global__ __launch_bounds__(256) void k_reduce(
    const float* __restrict__ h, const float* __restrict__ ef,
    const int* __restrict__ cnt, const int* __restrict__ off,
    const float2* __restrict__ dp, const i32x4* __restrict__ recA,
    short* __restrict__ hb)
{
    int n = blockIdx.x * 4 + (threadIdx.x >> 6);
    if (n >= NN) return;
    int lane = threadIdx.x & 63;
    bool up = lane >= 32;
    int l5 = lane & 31;
    int deg = cnt[n], base = off[n];
    const i32x4* rp = recA + base;
    float acch = 0.f, acce = 0.f, den = 0.f;
    int j = 0;
    for (; j + 8 <= deg; j += 8) {
        i32x4 r[8];
        #pragma unroll
        for (int t = 0; t < 8; ++t) r[t] = rp[j + t];
        float2 dv[8];
        #pragma unroll
        for (int t = 0; t < 8; ++t) dv[t] = dp[r[t][0]];
        float hv[8];
        #pragma unroll
        for (int t = 0; t < 8; ++t) hv[t] = h[((unsigned)r[t][0] << 6) + lane];
        float efv[4];
        #pragma unroll
        for (int t = 0; t < 4; ++t) {
            int e = up ? r[2*t+1][1] : r[2*t][1];
            efv[t] = ef[((unsigned)e << 5) + l5];
        }
        float g[8], s[8];
        #pragma unroll
        for (int t = 0; t < 8; ++t) {
            g[t] = __int_as_float(r[t][2]) * __builtin_amdgcn_rcpf(dv[t].x);
            s[t] = __expf(dv[t].y + g[t] * __int_as_float(r[t][3]));
            den  += s[t];
            acch += s[t] * hv[t];
        }
        #pragma unroll
        for (int t = 0; t < 4; ++t) {
            float w = up ? s[2*t+1]*g[2*t+1] : s[2*t]*g[2*t];
            acce += w * efv[t];
        }
    }
    if (j + 4 <= deg) {
        i32x4 r[4];
        #pragma unroll
        for (int t = 0; t < 4; ++t) r[t] = rp[j + t];
        float2 dv[4];
        #pragma unroll
        for (int t = 0; t < 4; ++t) dv[t] = dp[r[t][0]];
        float hv[4];
        #pragma unroll
        for (int t = 0; t < 4; ++t) hv[t] = h[((unsigned)r[t][0] << 6) + lane];
        float efv[2];
        #pragma unroll
        for (int t = 0; t < 2; ++t) {
            int e = up ? r[2*t+1][1] : r[2*t][1];
            efv[t] = ef[((unsigned)e << 5) + l5];
        }
        float g[4], s[4];
        #pragma unroll
        for (int t = 0; t < 4; ++t) {
            g[t] = __int_as_float(r[t][2]) * __builtin_amdgcn_rcpf(dv[t].x);
            s[t] = __expf(dv[t].y + g[t] * __int_as_float(r[t][3]));
            den  += s[t];
            acch += s[t] * hv[t];
        }
        #pragma unroll
        for (int t = 0; t < 2; ++t) {
            float w = up ? s[2*t+1]*g[2*t+1] : s[2*t]*g[2*t];
            acce += w * efv[t];
        }
        j += 4;
    }
    for (; j < deg; ++j) {
        i32x4 r = rp[j];
        float2 dt = dp[r[0]];
        float g = __int_as_float(r[2]) * __builtin_amdgcn_rcpf(dt.x);
        float s = __expf(dt.y + g * __int_as_float(r[3]));
        den += s;
        acch += s * h[((unsigned)r[0] << 6) + lane];
        if (!up) acce += s * g * ef[((unsigned)r[1] << 5) + l5];
    }
    acce += __shfl_xor(acce, 32);          // fold odd-record (upper-lane) part
    float inv = (deg > 0) ? __builtin_amdgcn_rcpf(den) : 0.f;
    size_t hbase = (size_t)n * 160;
    hb[hbase + 64 + lane] = f2bf(acch * inv);
    if (!up) hb[hbase + 128 + l5] = f2bf(acce * inv);
}

// ---------------------------------------------------------------------------
// Pass 4: out = relu(hb @ w_lin) as an MFMA bf16 GEMM. A rows are already
// bf16 in hb[n][160] -> one 16B load per k-chunk, zero conversion in the hot
// loop. One 16-node tile per wave, grid 782 blocks (3128 waves, ~3/SIMD) --
// the old 256-block config ran 1 wave/SIMD with fully-exposed load latency.
// Layouts (m89/m120-verified): A[m=lane&15][k=quad*8+j],
// B[k=quad*8+j][n=lane&15], D[row=quad*4+reg][col=lane&15].
// ---------------------------------------------------------------------------
__global__ __launch_bounds__(256) void k_node_update(
    const short* __restrict__ hb, const float* __restrict__ wl_g,
    float* __restrict__ out)
{
    int lane = threadIdx.x & 63;
    int col  = lane & 15;
    int quad = lane >> 4;
    int tile = blockIdx.x * 4 + (threadIdx.x >> 6);
    if (tile >= NTILES) return;

    bf16x8 bfr[5][4];
    #pragma unroll
    for (int kc = 0; kc < 5; ++kc)
        #pragma unroll
        for (int nt = 0; nt < 4; ++nt) {
            #pragma unroll
            for (int j = 0; j < 8; ++j) {
                int k = kc * 32 + quad * 8 + j;
                bfr[kc][nt][j] = f2bf(wl_g[k * 64 + nt * 16 + col]);
            }
        }

    int n = tile * 16 + col;                 // A-operand node (m = lane&15)
    f32x4 acc[4];
    #pragma unroll
    for (int nt = 0; nt < 4; ++nt) acc[nt] = (f32x4){0.f, 0.f, 0.f, 0.f};

    const short* hrow = hb + (size_t)n * 160 + quad * 8;
    #pragma unroll
    for (int kc = 0; kc < 5; ++kc) {
        bf16x8 af = *(const bf16x8*)(hrow + kc * 32);
        #pragma unroll
        for (int nt = 0; nt < 4; ++nt)
            acc[nt] = __builtin_amdgcn_mfma_f32_16x16x32_bf16(
                af, bfr[kc][nt], acc[nt], 0, 0, 0);
    }

    // D: row = quad*4 + r (node within tile), col = nt*16 + (lane&15)
    #pragma unroll
    for (int nt = 0; nt < 4; ++nt) {
        #pragma unroll
        for (int r = 0; r < 4; ++r) {
            int node = tile * 16 + quad * 4 + r;
            out[(size_t)node * 64 + nt * 16 + col] = fmaxf(acc[nt][r], 0.f);
        }
    }
}

// ---------------------------------------------------------------------------
// Workspace layout (4-byte words):
//   [0, 2NN)            dp      (float2 {den_src, p3}; zeroed)
//   [2NN, 3NN)          cnt     (int, zeroed)
//   [3NN, 3NN+16)       gtotal  (int, zeroed)
//   [3NN+16, 4NN+16)    off     (int)
//   [4NN+16, 5NN+16)    p1      (float)
//   [5NN+16, 6NN+16)    pd      (float)
//   [6NN+16, +4NE)      recA    (i32x4; byte off 1200064 %16==0)
//   [+4NE, +5NE)        rank    (int, NE; dead after k_edge)
//   [+5NE, +5NE+80NN)   hb      (bf16 [NN][160]; byte off 17200064 %16==0)
// total = 6NN+16 + 5NE + 80NN words = 8,300,016 words = 33.2 MB (same as before)
// ---------------------------------------------------------------------------
extern "C" void kernel_launch(void* const* d_in, const int* in_sizes, int n_in,
                              void* d_out, int out_size, void* d_ws, size_t ws_size,
                              hipStream_t stream)
{
    const float* h   = (const float*)d_in[0];
    const float* ef  = (const float*)d_in[1];
    const int*   src = (const int*)d_in[2];
    const int*   dst = (const int*)d_in[3];
    const float* wg  = (const float*)d_in[4];
    const float* wa  = (const float*)d_in[5];
    const float* wl  = (const float*)d_in[6];
    float* out = (float*)d_out;

    float* ws = (float*)d_ws;
    float*  dpf    = ws;                       // float2 view at same addr
    int*    cnt    = (int*)(ws + 2 * NN);
    int*    gtotal = (int*)(ws + 3 * NN);
    int*    off    = (int*)(ws + 3 * NN + 16);
    float*  p1     = ws + 4 * NN + 16;
    float*  pd     = ws + 5 * NN + 16;
    i32x4*  recA   = (i32x4*)(ws + 6 * NN + 16);
    int*    rank   = (int*)(ws + 6 * NN + 16 + 4 * NE);
    short*  hb     = (short*)(ws + 6 * NN + 16 + 5 * NE);

    hipMemsetAsync(d_ws, 0, (size_t)(3 * NN + 16) * sizeof(float), stream);

    k_pre<<<NEB + NHB, 256, 0, stream>>>(h, dst, wg, wa, cnt, rank, p1, pd, dpf, hb);
    k_assign<<<(NN + 255) / 256, 256, 0, stream>>>(cnt, off, gtotal);
    k_edge<<<NEB, 256, 0, stream>>>(ef, src, dst, rank, wg, wa, p1, pd, dpf,
                                    off, recA);
    k_reduce<<<(NN + 3) / 4, 256, 0, stream>>>(h, ef, cnt, off, (const float2*)dpf,
                                               recA, hb);
    k_node_update<<<782, 256, 0, stream>>>(hb, wl, out);
}

// Round 2
// 352.671 us; speedup vs baseline: 1.0104x; 1.0104x over previous
//
#include <hip/hip_runtime.h>

#define NN 50000
#define NE 800000
#define NEB 3125   // NE/256 edge blocks (1 edge/thread)
#define NHB 3125   // NN/16 projection blocks / node tiles
#define NTILES 3125
// inputs: node_features[NN*64] f32, edge_features[NE*32] f32, src[NE] i32,
//         dst[NE] i32, w_group[160] f32, w_srcattn[96] f32, w_lin[160*64] f32
// out: [NN*64] f32
//
// Algebra: a = ef·wg[0:32] + p1[src] + p2[dst]; t = p3[src]; u = ef·wa[64:96]
//          gamma = e^a / den_src[src]; s = t + gamma*u
// dst-CSR via hist(rank)+assign. k_edge scatters ONLY a 4B edge index
// (eidx[pos]=e); the 8B payload {e^a,u} is written coalesced at recB[e].
// The 3.2MB eidx region is L2-resident per XCD -> partial lines merge
// before writeback (vs 16B record scatter = 64B writeback per edge).
// hb[n][160] bf16 row = [bf16(h) | accum] is the GEMM A-matrix.

typedef __attribute__((ext_vector_type(8))) short bf16x8;  // 8 bf16 (4 VGPRs)
typedef __attribute__((ext_vector_type(4))) short s16x4;
typedef __attribute__((ext_vector_type(4))) float f32x4;

static __device__ __forceinline__ short f2bf(float f) {
    unsigned int u = __float_as_uint(f);
    u += 0x7FFFu + ((u >> 16) & 1u);       // round-to-nearest-even
    return (short)(u >> 16);
}

// ---------------------------------------------------------------------------
// Pass 0a: dst histogram + per-edge rank. 1 edge/thread (round-1's 2/thread
// halved occupancy and regressed). Split from the projection kernel for
// rocprof visibility of the atomic-return cost.
// ---------------------------------------------------------------------------
__global__ __launch_bounds__(256) void k_hist(
    const int* __restrict__ dst, int* __restrict__ cnt, int* __restrict__ rank)
{
    int e = blockIdx.x * 256 + threadIdx.x;
    if (e < NE) rank[e] = atomicAdd(&cnt[dst[e]], 1);
}

// ---------------------------------------------------------------------------
// Pass 0b: per-node projections (16 lanes/node, shfl reduce)
//   p1 = h·wg[32:96] ; pdo[n].x = bits(h·wg[96:160]) ; dp[n].y = h·wa[0:64]
// plus bf16 copy of the h row into hb[n][0:64] for the final GEMM.
// ---------------------------------------------------------------------------
__global__ __launch_bounds__(256) void k_proj(
    const float* __restrict__ h, const float* __restrict__ wg,
    const float* __restrict__ wa, float* __restrict__ p1,
    int2* __restrict__ pdo, float* __restrict__ dpf, short* __restrict__ hb)
{
    __shared__ float4 ls[16], ld[16], lt[16];
    int tid = threadIdx.x;
    if (tid < 16)      ls[tid]      = ((const float4*)wg)[8 + tid];   // wg[32:96)
    else if (tid < 32) ld[tid - 16] = ((const float4*)wg)[8 + tid];   // wg[96:160)
    else if (tid < 48) lt[tid - 32] = ((const float4*)wa)[tid - 32];  // wa[0:64)
    __syncthreads();
    int n = blockIdx.x * 16 + (tid >> 4);
    if (n >= NN) return;
    int l16 = tid & 15;
    float4 v = ((const float4*)(h + (size_t)n * 64))[l16];
    s16x4 hv;
    hv[0] = f2bf(v.x); hv[1] = f2bf(v.y); hv[2] = f2bf(v.z); hv[3] = f2bf(v.w);
    *(s16x4*)(hb + (size_t)n * 160 + l16 * 4) = hv;
    float4 w1 = ls[l16], w2 = ld[l16], w3 = lt[l16];
    float s1 = v.x*w1.x + v.y*w1.y + v.z*w1.z + v.w*w1.w;
    float s2 = v.x*w2.x + v.y*w2.y + v.z*w2.z + v.w*w2.w;
    float s3 = v.x*w3.x + v.y*w3.y + v.z*w3.z + v.w*w3.w;
    #pragma unroll
    for (int m = 8; m; m >>= 1) {
        s1 += __shfl_xor(s1, m);
        s2 += __shfl_xor(s2, m);
        s3 += __shfl_xor(s3, m);
    }
    if (l16 == 0) {
        p1[n] = s1;
        pdo[n].x = __float_as_int(s2);
        dpf[2 * n + 1] = s3;
    }
}

// ---------------------------------------------------------------------------
// Pass 1: contiguous (order-arbitrary) segment bases from cnt -> pdo[n].y.
// ---------------------------------------------------------------------------
__global__ __launch_bounds__(256) void k_assign(
    const int* __restrict__ cnt, int2* __restrict__ pdo, int* __restrict__ gtotal)
{
    int n = blockIdx.x * 256 + threadIdx.x;
    int lane = threadIdx.x & 63;
    int c = (n < NN) ? cnt[n] : 0;
    int pre = c;
    #pragma unroll
    for (int d = 1; d < 64; d <<= 1) {
        int v = __shfl_up(pre, d);
        if (lane >= d) pre += v;
    }
    int base = 0;
    if (lane == 63) base = atomicAdd(gtotal, pre);
    base = __shfl(base, 63);
    if (n < NN) pdo[n].y = base + pre - c;
}

// ---------------------------------------------------------------------------
// Pass 2: edge scoring, 1 edge/thread. {pd,off} packed in one int2 gather.
// Coalesced 8B payload write recB[e]={e^a,u}; 4B CSR scatter eidx[pos]=e.
// den atomic is fire-and-forget.
// ---------------------------------------------------------------------------
__global__ __launch_bounds__(256) void k_edge(
    const float* __restrict__ ef, const int* __restrict__ src,
    const int* __restrict__ dst, const int* __restrict__ rank,
    const float* __restrict__ wg, const float* __restrict__ wa,
    const float* __restrict__ p1, const int2* __restrict__ pdo,
    float* __restrict__ dpf, int* __restrict__ eidx,
    float2* __restrict__ recB)
{
    __shared__ float4 lwe[8], lae[8];
    int tid = threadIdx.x;
    if (tid < 8)       lwe[tid]     = ((const float4*)wg)[tid];          // wg[0:32)
    else if (tid < 16) lae[tid - 8] = ((const float4*)wa)[tid - 8 + 16]; // wa[64:96)
    __syncthreads();
    int e = blockIdx.x * 256 + tid;
    if (e >= NE) return;
    int s = src[e], d = dst[e], rk = rank[e];
    float p1v = p1[s];
    int2 pv = pdo[d];
    float pdv = __int_as_float(pv.x);
    int pos = pv.y + rk;
    const float4* e4 = (const float4*)(ef + (size_t)e * 32);
    float a = 0.f, u = 0.f;
    #pragma unroll
    for (int q = 0; q < 8; ++q) {
        float4 v = e4[q], w = lwe[q], w2 = lae[q];
        a += v.x*w.x  + v.y*w.y  + v.z*w.z  + v.w*w.w;
        u += v.x*w2.x + v.y*w2.y + v.z*w2.z + v.w*w2.w;
    }
    float ev = __expf(a + p1v + pdv);
    atomicAdd(&dpf[2 * s], ev);            // den_src; no return needed
    recB[e] = make_float2(ev, u);          // coalesced payload
    eidx[pos] = e;                         // 4B scatter (L2-resident region)
}

// ---------------------------------------------------------------------------
// Pass 3: wave-per-node segmented softmax-reduce, 8-wide main loop.
// Gather chain per record: eidx (coalesced) -> recB[e]/src[e] (L2 tables)
// -> dp[s] / h-row / ef-row. Same numerics as before (identical ev/u bits).
// ef rows: lanes>=32 take the odd record of each pair; one shfl_xor(32) fold.
// bf16 accum store into hb[n][64:160].
// ---------------------------------------------------------------------------
__global__ __launch_bounds__(256) void k_reduce(
    const float* __restrict__ h, const float* __restrict__ ef,
    const int* __restrict__ src, const int* __restrict__ cnt,
    const int2* __restrict__ pdo, const float2* __restrict__ dp,
    const int* __restrict__ eidx, const float2* __restrict__ recB,
    short* __restrict__ hb)
{
    int n = blockIdx.x * 4 + (threadIdx.x >> 6);
    if (n >= NN) return;
    int lane = threadIdx.x & 63;
    bool up = lane >= 32;
    int l5 = lane & 31;
    int deg = cnt[n], base = pdo[n].y;
    const int* ep = eidx + base;
    float acch = 0.f, acce = 0.f, den = 0.f;
    int j = 0;
    for (; j + 8 <= deg; j += 8) {
        int e[8];
        #pragma unroll
        for (int t = 0; t < 8; ++t) e[t] = ep[j + t];
        float2 rb[8]; int sv[8];
        #pragma unroll
        for (int t = 0; t < 8; ++t) { rb[t] = recB[e[t]]; sv[t] = src[e[t]]; }
        float2 dv[8]; float hv[8];
        #pragma unroll
        for (int t = 0; t < 8; ++t) {
            dv[t] = dp[sv[t]];
            hv[t] = h[((unsigned)sv[t] << 6) + lane];
        }
        float efv[4];
        #pragma unroll
        for (int t = 0; t < 4; ++t) {
            int ee = up ? e[2*t+1] : e[2*t];
            efv[t] = ef[((unsigned)ee << 5) + l5];
        }
        float g[8], s[8];
        #pragma unroll
        for (int t = 0; t < 8; ++t) {
            g[t] = rb[t].x * __builtin_amdgcn_rcpf(dv[t].x);
            s[t] = __expf(dv[t].y + g[t] * rb[t].y);
            den  += s[t];
            acch += s[t] * hv[t];
        }
        #pragma unroll
        for (int t = 0; t < 4; ++t) {
            float w = up ? s[2*t+1]*g[2*t+1] : s[2*t]*g[2*t];
            acce += w * efv[t];
        }
    }
    if (j + 4 <= deg) {
        int e[4];
        #pragma unroll
        for (int t = 0; t < 4; ++t) e[t] = ep[j + t];
        float2 rb[4]; int sv[4];
        #pragma unroll
        for (int t = 0; t < 4; ++t) { rb[t] = recB[e[t]]; sv[t] = src[e[t]]; }
        float2 dv[4]; float hv[4];
        #pragma unroll
        for (int t = 0; t < 4; ++t) {
            dv[t] = dp[sv[t]];
            hv[t] = h[((unsigned)sv[t] << 6) + lane];
        }
        float efv[2];
        #pragma unroll
        for (int t = 0; t < 2; ++t) {
            int ee = up ? e[2*t+1] : e[2*t];
            efv[t] = ef[((unsigned)ee << 5) + l5];
        }
        float g[4], s[4];
        #pragma unroll
        for (int t = 0; t < 4; ++t) {
            g[t] = rb[t].x * __builtin_amdgcn_rcpf(dv[t].x);
            s[t] = __expf(dv[t].y + g[t] * rb[t].y);
            den  += s[t];
            acch += s[t] * hv[t];
        }
        #pragma unroll
        for (int t = 0; t < 2; ++t) {
            float w = up ? s[2*t+1]*g[2*t+1] : s[2*t]*g[2*t];
            acce += w * efv[t];
        }
        j += 4;
    }
    for (; j < deg; ++j) {
        int e = ep[j];
        float2 rb = recB[e];
        int s0 = src[e];
        float2 dt = dp[s0];
        float g = rb.x * __builtin_amdgcn_rcpf(dt.x);
        float sx = __expf(dt.y + g * rb.y);
        den += sx;
        acch += sx * h[((unsigned)s0 << 6) + lane];
        if (!up) acce += sx * g * ef[((unsigned)e << 5) + l5];
    }
    acce += __shfl_xor(acce, 32);          // fold odd-record (upper-lane) part
    float inv = (deg > 0) ? __builtin_amdgcn_rcpf(den) : 0.f;
    size_t hbase = (size_t)n * 160;
    hb[hbase + 64 + lane] = f2bf(acch * inv);
    if (!up) hb[hbase + 128 + l5] = f2bf(acce * inv);
}

// ---------------------------------------------------------------------------
// Pass 4: out = relu(hb @ w_lin) as an MFMA bf16 GEMM. A rows are already
// bf16 in hb[n][160] -> one 16B load per k-chunk. One 16-node tile per wave,
// 782 blocks (~3 waves/SIMD).
// Layouts (m89/m120-verified): A[m=lane&15][k=quad*8+j],
// B[k=quad*8+j][n=lane&15], D[row=quad*4+reg][col=lane&15].
// ---------------------------------------------------------------------------
__global__ __launch_bounds__(256) void k_node_update(
    const short* __restrict__ hb, const float* __restrict__ wl_g,
    float* __restrict__ out)
{
    int lane = threadIdx.x & 63;
    int col  = lane & 15;
    int quad = lane >> 4;
    int tile = blockIdx.x * 4 + (threadIdx.x >> 6);
    if (tile >= NTILES) return;

    bf16x8 bfr[5][4];
    #pragma unroll
    for (int kc = 0; kc < 5; ++kc)
        #pragma unroll
        for (int nt = 0; nt < 4; ++nt) {
            #pragma unroll
            for (int j = 0; j < 8; ++j) {
                int k = kc * 32 + quad * 8 + j;
                bfr[kc][nt][j] = f2bf(wl_g[k * 64 + nt * 16 + col]);
            }
        }

    int n = tile * 16 + col;                 // A-operand node (m = lane&15)
    f32x4 acc[4];
    #pragma unroll
    for (int nt = 0; nt < 4; ++nt) acc[nt] = (f32x4){0.f, 0.f, 0.f, 0.f};

    const short* hrow = hb + (size_t)n * 160 + quad * 8;
    #pragma unroll
    for (int kc = 0; kc < 5; ++kc) {
        bf16x8 af = *(const bf16x8*)(hrow + kc * 32);
        #pragma unroll
        for (int nt = 0; nt < 4; ++nt)
            acc[nt] = __builtin_amdgcn_mfma_f32_16x16x32_bf16(
                af, bfr[kc][nt], acc[nt], 0, 0, 0);
    }

    // D: row = quad*4 + r (node within tile), col = nt*16 + (lane&15)
    #pragma unroll
    for (int nt = 0; nt < 4; ++nt) {
        #pragma unroll
        for (int r = 0; r < 4; ++r) {
            int node = tile * 16 + quad * 4 + r;
            out[(size_t)node * 64 + nt * 16 + col] = fmaxf(acc[nt][r], 0.f);
        }
    }
}

// ---------------------------------------------------------------------------
// Workspace layout (4-byte words):
//   [0, 2NN)                 dp    (float2 {den_src, p3}; zeroed)
//   [2NN, 3NN)               cnt   (int, zeroed)
//   [3NN, 3NN+16)            gtotal(int, zeroed)
//   [3NN+16, 5NN+16)         pdo   (int2 {bits(pd), off})
//   [5NN+16, 6NN+16)         p1    (float)
//   [6NN+16, +NE)            rank  (int)
//   [+NE, +2NE)              eidx  (int; CSR edge index)
//   [+2NE, +4NE)             recB  (float2 {e^a, u}; byte off 7600064 %8==0)
//   [+4NE, +4NE+80NN)        hb    (bf16 [NN][160]; byte off 14000064 %16==0)
// total = 6NN+16 + 4NE + 80NN words = 7,500,016 words = 30.0 MB (< old 33.2)
// ---------------------------------------------------------------------------
extern "C" void kernel_launch(void* const* d_in, const int* in_sizes, int n_in,
                              void* d_out, int out_size, void* d_ws, size_t ws_size,
                              hipStream_t stream)
{
    const float* h   = (const float*)d_in[0];
    const float* ef  = (const float*)d_in[1];
    const int*   src = (const int*)d_in[2];
    const int*   dst = (const int*)d_in[3];
    const float* wg  = (const float*)d_in[4];
    const float* wa  = (const float*)d_in[5];
    const float* wl  = (const float*)d_in[6];
    float* out = (float*)d_out;

    float*  ws     = (float*)d_ws;
    float*  dpf    = ws;                       // float2 view at same addr
    int*    cnt    = (int*)(ws + 2 * NN);
    int*    gtotal = (int*)(ws + 3 * NN);
    int2*   pdo    = (int2*)(ws + 3 * NN + 16);
    float*  p1     = ws + 5 * NN + 16;
    int*    rank   = (int*)(ws + 6 * NN + 16);
    int*    eidx   = (int*)(ws + 6 * NN + 16 + NE);
    float2* recB   = (float2*)(ws + 6 * NN + 16 + 2 * NE);
    short*  hb     = (short*)(ws + 6 * NN + 16 + 4 * NE);

    hipMemsetAsync(d_ws, 0, (size_t)(3 * NN + 16) * sizeof(float), stream);

    k_hist<<<NEB, 256, 0, stream>>>(dst, cnt, rank);
    k_proj<<<NHB, 256, 0, stream>>>(h, wg, wa, p1, pdo, dpf, hb);
    k_assign<<<(NN + 255) / 256, 256, 0, stream>>>(cnt, pdo, gtotal);
    k_edge<<<NEB, 256, 0, stream>>>(ef, src, dst, rank, wg, wa, p1, pdo,
                                    dpf, eidx, recB);
    k_reduce<<<(NN + 3) / 4, 256, 0, stream>>>(h, ef, src, cnt, pdo,
                                               (const float2*)dpf, eidx, recB, hb);
    k_node_update<<<782, 256, 0, stream>>>(hb, wl, out);
}